// Round 8
// baseline (122.590 us; speedup 1.0000x reference)
//
#include <hip/hip_runtime.h>
#include <hip/hip_fp16.h>

#define DD 64
#define NPB 64          // nodes per block (node kernel)
#define LP 72           // padded LDS row stride in halves (144 B): 2-way-only bank aliasing

typedef _Float16 f16x8 __attribute__((ext_vector_type(8)));
typedef float    f32x4 __attribute__((ext_vector_type(4)));

// Node-level transform on MFMA f16 (fp32 accumulate):
//   A = (K_h + P_e) @ W1 + b1   (stored fp16)
//   B = Q_h @ W1                (stored fp16)
__global__ __launch_bounds__(256) void node_transform_mfma(
    const float* __restrict__ K_h, const float* __restrict__ Q_h,
    const float* __restrict__ P_e, const float* __restrict__ W1,
    const float* __restrict__ b1, __half* __restrict__ A,
    __half* __restrict__ Bm, int n_nodes)
{
    __shared__ __half XH [NPB][LP];   // fp16(K+P)
    __shared__ __half QH [NPB][LP];   // fp16(Q)
    __shared__ __half W1T[DD][LP];    // W1 transposed: W1T[n][k] = W1[k][n]

    const int tid   = threadIdx.x;
    const int nbase = blockIdx.x * NPB;

    // ---- Stage W1T (8 KB): thread t reads W1[k][n0..n0+15], scatters column-wise ----
    {
        const int k  = tid >> 2;
        const int n0 = (tid & 3) << 4;
        const float* wr = W1 + k * DD + n0;
        float4 w0 = *(const float4*)(wr);
        float4 w1v = *(const float4*)(wr + 4);
        float4 w2v = *(const float4*)(wr + 8);
        float4 w3v = *(const float4*)(wr + 12);
        const float wv[16] = {w0.x,w0.y,w0.z,w0.w, w1v.x,w1v.y,w1v.z,w1v.w,
                              w2v.x,w2v.y,w2v.z,w2v.w, w3v.x,w3v.y,w3v.z,w3v.w};
#pragma unroll
        for (int j = 0; j < 16; ++j)
            W1T[n0 + j][k] = __float2half(wv[j]);
    }

    // ---- Stage XH = fp16(K+P), QH = fp16(Q); coalesced float4 global reads ----
#pragma unroll
    for (int ch = 0; ch < 4; ++ch) {
        int idx = tid + (ch << 8);        // float4 index over [64 rows][16]
        int r   = idx >> 4;
        int q4  = idx & 15;
        int node = nbase + r;
        float4 kv = make_float4(0.f,0.f,0.f,0.f);
        float4 pv = kv, qv = kv;
        if (node < n_nodes) {
            kv = *(const float4*)(K_h + (size_t)node * DD + q4 * 4);
            pv = *(const float4*)(P_e + (size_t)node * DD + q4 * 4);
            qv = *(const float4*)(Q_h + (size_t)node * DD + q4 * 4);
        }
        __half2* xh = (__half2*)&XH[r][q4 << 2];
        xh[0] = __float22half2_rn(make_float2(kv.x + pv.x, kv.y + pv.y));
        xh[1] = __float22half2_rn(make_float2(kv.z + pv.z, kv.w + pv.w));
        __half2* qh = (__half2*)&QH[r][q4 << 2];
        qh[0] = __float22half2_rn(make_float2(qv.x, qv.y));
        qh[1] = __float22half2_rn(make_float2(qv.z, qv.w));
    }
    __syncthreads();

    // ---- MFMA main: wave w, lane (m = lane&15, q = lane>>4) ----
    const int w    = tid >> 6;
    const int lane = tid & 63;
    const int m    = lane & 15;
    const int q    = lane >> 4;
    const int row  = (w << 4) + m;

    f16x8 xlo = *(const f16x8*)&XH[row][(q << 3)];
    f16x8 xhi = *(const f16x8*)&XH[row][32 + (q << 3)];
    f16x8 qlo = *(const f16x8*)&QH[row][(q << 3)];
    f16x8 qhi = *(const f16x8*)&QH[row][32 + (q << 3)];

    f32x4 accA[4], accB[4];
#pragma unroll
    for (int t = 0; t < 4; ++t) {
        float bb = b1[t * 16 + m];            // b1 folded into A accumulator
        accA[t] = (f32x4){bb, bb, bb, bb};
        accB[t] = (f32x4){0.f, 0.f, 0.f, 0.f};
        f16x8 wlo = *(const f16x8*)&W1T[t * 16 + m][(q << 3)];
        f16x8 whi = *(const f16x8*)&W1T[t * 16 + m][32 + (q << 3)];
        accA[t] = __builtin_amdgcn_mfma_f32_16x16x32_f16(xlo, wlo, accA[t], 0, 0, 0);
        accA[t] = __builtin_amdgcn_mfma_f32_16x16x32_f16(xhi, whi, accA[t], 0, 0, 0);
        accB[t] = __builtin_amdgcn_mfma_f32_16x16x32_f16(qlo, wlo, accB[t], 0, 0, 0);
        accB[t] = __builtin_amdgcn_mfma_f32_16x16x32_f16(qhi, whi, accB[t], 0, 0, 0);
    }

    // ---- Store: acc[t][r] -> out[nbase + w*16 + q*4 + r][t*16 + m] ----
#pragma unroll
    for (int r = 0; r < 4; ++r) {
        int node = nbase + (w << 4) + (q << 2) + r;
        if (node >= n_nodes) continue;
        __half* Arow = A  + (size_t)node * DD + m;
        __half* Brow = Bm + (size_t)node * DD + m;
#pragma unroll
        for (int t = 0; t < 4; ++t) {
            Arow[t * 16] = __float2half(accA[t][r]);
            Brow[t * 16] = __float2half(accB[t][r]);
        }
    }
}

// Edge-level: score[e] = relu(A[src[e]] - B[dst[e]]) . W2 + b2
// 8 lanes per edge, 4 edges per lane-group, GRID-STRIDE + SW PIPELINE:
// the next iteration's int4 indices are loaded while the current iteration's
// 8 row-gathers are in flight, removing the idx->gather dependency from the
// per-wave critical path (R7 analysis: bursty in-flight duty cycle was the
// remaining latency-overlap suspect).
__global__ __launch_bounds__(256) void edge_score_kernel(
    const __half* __restrict__ A, const __half* __restrict__ Bm,
    const int* __restrict__ src, const int* __restrict__ dst,
    const float* __restrict__ W2, const float* __restrict__ b2,
    float* __restrict__ out, int n_edges)
{
    const int tid = threadIdx.x;
    const int g   = tid >> 3;                   // lane-group 0..31
    const int c   = tid & 7;                    // 16B chunk within row
    const int ngroups = (n_edges + 3) >> 2;
    const int gstride = gridDim.x << 5;         // groups per grid sweep

    float4 w0 = *(const float4*)(W2 + c * 8);   // uniform -> s_load
    float4 w1 = *(const float4*)(W2 + c * 8 + 4);
    const float wv[8] = {w0.x, w0.y, w0.z, w0.w, w1.x, w1.y, w1.z, w1.w};
    const float bb = b2[0];
    const size_t coff = (size_t)(c * 8);

    int gid = (blockIdx.x << 5) + g;

    // Prologue: indices for the first iteration.
    int4 sv = make_int4(0, 0, 0, 0), dv = sv;
    if (gid < ngroups && (gid << 2) + 3 < n_edges) {
        sv = *(const int4*)(src + (gid << 2));
        dv = *(const int4*)(dst + (gid << 2));
    }

    while (gid < ngroups) {
        const int e0 = gid << 2;
        const int gid_next = gid + gstride;

        if (e0 + 3 < n_edges) {
            // Issue all 8 row gathers back-to-back.
            float4 ra0 = *(const float4*)(A  + (size_t)sv.x * DD + coff);
            float4 rb0 = *(const float4*)(Bm + (size_t)dv.x * DD + coff);
            float4 ra1 = *(const float4*)(A  + (size_t)sv.y * DD + coff);
            float4 rb1 = *(const float4*)(Bm + (size_t)dv.y * DD + coff);
            float4 ra2 = *(const float4*)(A  + (size_t)sv.z * DD + coff);
            float4 rb2 = *(const float4*)(Bm + (size_t)dv.z * DD + coff);
            float4 ra3 = *(const float4*)(A  + (size_t)sv.w * DD + coff);
            float4 rb3 = *(const float4*)(Bm + (size_t)dv.w * DD + coff);

            // Prefetch next iteration's indices while gathers are in flight.
            int4 svn = make_int4(0, 0, 0, 0), dvn = svn;
            if (gid_next < ngroups && (gid_next << 2) + 3 < n_edges) {
                svn = *(const int4*)(src + (gid_next << 2));
                dvn = *(const int4*)(dst + (gid_next << 2));
            }

            float acc0 = 0.f, acc1 = 0.f, acc2 = 0.f, acc3 = 0.f;
            const __half2* ah0 = (const __half2*)&ra0;
            const __half2* bh0 = (const __half2*)&rb0;
            const __half2* ah1 = (const __half2*)&ra1;
            const __half2* bh1 = (const __half2*)&rb1;
            const __half2* ah2 = (const __half2*)&ra2;
            const __half2* bh2 = (const __half2*)&rb2;
            const __half2* ah3 = (const __half2*)&ra3;
            const __half2* bh3 = (const __half2*)&rb3;
#pragma unroll
            for (int j = 0; j < 4; ++j) {
                float2 x, y;
                x = __half22float2(ah0[j]); y = __half22float2(bh0[j]);
                acc0 = fmaf(fmaxf(x.x - y.x, 0.f), wv[2 * j + 0], acc0);
                acc0 = fmaf(fmaxf(x.y - y.y, 0.f), wv[2 * j + 1], acc0);
                x = __half22float2(ah1[j]); y = __half22float2(bh1[j]);
                acc1 = fmaf(fmaxf(x.x - y.x, 0.f), wv[2 * j + 0], acc1);
                acc1 = fmaf(fmaxf(x.y - y.y, 0.f), wv[2 * j + 1], acc1);
                x = __half22float2(ah2[j]); y = __half22float2(bh2[j]);
                acc2 = fmaf(fmaxf(x.x - y.x, 0.f), wv[2 * j + 0], acc2);
                acc2 = fmaf(fmaxf(x.y - y.y, 0.f), wv[2 * j + 1], acc2);
                x = __half22float2(ah3[j]); y = __half22float2(bh3[j]);
                acc3 = fmaf(fmaxf(x.x - y.x, 0.f), wv[2 * j + 0], acc3);
                acc3 = fmaf(fmaxf(x.y - y.y, 0.f), wv[2 * j + 1], acc3);
            }

            acc0 += __shfl_xor(acc0, 1); acc1 += __shfl_xor(acc1, 1);
            acc2 += __shfl_xor(acc2, 1); acc3 += __shfl_xor(acc3, 1);
            acc0 += __shfl_xor(acc0, 2); acc1 += __shfl_xor(acc1, 2);
            acc2 += __shfl_xor(acc2, 2); acc3 += __shfl_xor(acc3, 2);
            acc0 += __shfl_xor(acc0, 4); acc1 += __shfl_xor(acc1, 4);
            acc2 += __shfl_xor(acc2, 4); acc3 += __shfl_xor(acc3, 4);

            if (c == 0) {
                *(float4*)(out + e0) =
                    make_float4(acc0 + bb, acc1 + bb, acc2 + bb, acc3 + bb);
            }
            sv = svn; dv = dvn;
        } else {
            // Scalar tail for the (rare) partial group.
            for (int e = e0; e < n_edges; ++e) {
                int s = src[e], d = dst[e];
                float4 ar = *(const float4*)(A  + (size_t)s * DD + coff);
                float4 br = *(const float4*)(Bm + (size_t)d * DD + coff);
                const __half2* ah = (const __half2*)&ar;
                const __half2* bh = (const __half2*)&br;
                float acc = 0.f;
#pragma unroll
                for (int j = 0; j < 4; ++j) {
                    float2 x = __half22float2(ah[j]);
                    float2 y = __half22float2(bh[j]);
                    acc = fmaf(fmaxf(x.x - y.x, 0.f), wv[2 * j + 0], acc);
                    acc = fmaf(fmaxf(x.y - y.y, 0.f), wv[2 * j + 1], acc);
                }
                acc += __shfl_xor(acc, 1);
                acc += __shfl_xor(acc, 2);
                acc += __shfl_xor(acc, 4);
                if (c == 0) out[e] = acc + bb;
            }
            // Reload indices for the next iteration (pipeline restart).
            if (gid_next < ngroups && (gid_next << 2) + 3 < n_edges) {
                sv = *(const int4*)(src + (gid_next << 2));
                dv = *(const int4*)(dst + (gid_next << 2));
            }
        }
        gid = gid_next;
    }
}

extern "C" void kernel_launch(void* const* d_in, const int* in_sizes, int n_in,
                              void* d_out, int out_size, void* d_ws, size_t ws_size,
                              hipStream_t stream) {
    const float* K_h = (const float*)d_in[0];
    const float* Q_h = (const float*)d_in[1];
    const float* P_e = (const float*)d_in[2];
    const int*   src = (const int*)d_in[3];
    const int*   dst = (const int*)d_in[4];
    const float* W1  = (const float*)d_in[5];
    const float* b1  = (const float*)d_in[6];
    const float* W2  = (const float*)d_in[7];
    const float* b2  = (const float*)d_in[8];
    float* out = (float*)d_out;

    int n_nodes = in_sizes[0] / DD;
    int n_edges = in_sizes[3];

    // Workspace: A [n][64] fp16, B [n][64] fp16 (12.8 MB total)
    __half* A  = (__half*)d_ws;
    __half* Bm = A + (size_t)n_nodes * DD;

    node_transform_mfma<<<(n_nodes + NPB - 1) / NPB, 256, 0, stream>>>(
        K_h, Q_h, P_e, W1, b1, A, Bm, n_nodes);

    // Grid-stride: 2048 blocks (8 per CU), ~3-4 pipelined iterations per wave.
    int ngroups = (n_edges + 3) >> 2;
    int nblocks = (ngroups + 31) / 32;
    if (nblocks > 2048) nblocks = 2048;
    edge_score_kernel<<<nblocks, 256, 0, stream>>>(
        A, Bm, src, dst, W2, b2, out, n_edges);
}